// Round 15
// baseline (3283.938 us; speedup 1.0000x reference)
//
#include <hip/hip_runtime.h>

#define L_SEQ 512
#define NB    64
#define DDIM  512
#define HHALF 256
#define GG    1024   // 4*HALF

using f32x4  = __attribute__((ext_vector_type(4))) float;
using u32x4  = __attribute__((ext_vector_type(4))) unsigned int;
using bf16x8 = __attribute__((ext_vector_type(8))) short;
using f16x8  = __attribute__((ext_vector_type(8))) _Float16;

__device__ __forceinline__ unsigned short f2bf(float f) {
    unsigned u = __float_as_uint(f);
    u += 0x7fffu + ((u >> 16) & 1u);          // round-to-nearest-even
    return (unsigned short)(u >> 16);
}
__device__ __forceinline__ float fsigmoid(float x) {
    return 1.0f / (1.0f + __expf(-x));
}
__device__ __forceinline__ float ftanh(float x) {
    return 1.0f - 2.0f / (__expf(2.0f * x) + 1.0f);
}

// --- device-coherent (memory-side L3) access helpers -----------------------
// sc0|sc1 on gfx950: bypass L1 + (non-cross-coherent) L2, access the
// device-coherent point. Used for all cross-block-shared data so NO
// buffer_wbl2 / buffer_inv cache maintenance is ever required.
__device__ __forceinline__ void st_dword_wt(unsigned int* p, unsigned int v) {
    asm volatile("global_store_dword %0, %1, off sc0 sc1" :: "v"(p), "v"(v) : "memory");
}
// v_cvt_pk_bf16_f32: 2 f32 -> packed 2x bf16 (RNE), one instruction (T12).
__device__ __forceinline__ unsigned cvt_pk_bf16(unsigned a, unsigned b) {
    unsigned d;
    asm("v_cvt_pk_bf16_f32 %0, %1, %2" : "=v"(d) : "v"(a), "v"(b));
    return d;
}

// ---------------------------------------------------------------------------
// Phase 1: xwb[dir][t][b][g] (fp16) = x[t][b][:] . W_ih[g][:] + b_ih[g] + b_hh[g]
// f16 MFMA GEMM, M=32768 (t*64+b), N=1024 (g), K=512, fp32 accumulate.
// No LDS: fragments loaded straight from global with the verified lane layout:
//   A frag : lane l holds A[row = l&15][k = (l>>4)*8 + j]   (8 f16, 4 VGPRs)
//   B frag : lane l holds B[k = (l>>4)*8 + j][col = l&15]  == W[col][k]
//   C/D    : lane l, reg r -> row = (l>>4)*4 + r, col = l&15
// Block = 256 thr = 4 waves; tile 64(M) x 256(N); wave w owns cols w*64..+63.
//
// EVERY block also zero-fills a 4096-float slice of `out` (64 MiB total,
// ~10 us of HBM writes spread over 4096 blocks). lstm_recur uses out itself
// as the h-exchange medium with mantissa-bit-0 as the "ready" tag, so
// "unwritten" must be exactly 0 (bit0=0) at the coherent point. Plain
// stores suffice: the dispatch-boundary release (which exists precisely to
// give cross-XCD visibility between same-stream kernels) writes back dirty
// L2 before lstm starts, and all lstm accesses to out are sc0|sc1.
// ---------------------------------------------------------------------------
__global__ __launch_bounds__(256) void gemm_xwb(
    const float* __restrict__ x,
    const float* __restrict__ Wf, const float* __restrict__ Wb,
    const float* __restrict__ bihf, const float* __restrict__ bhhf,
    const float* __restrict__ bihb, const float* __restrict__ bhhb,
    _Float16* __restrict__ xwb,
    float* __restrict__ out_zero)
{
    const int dir = blockIdx.z;
    const float* __restrict__ W   = dir ? Wb   : Wf;
    const float* __restrict__ bih = dir ? bihb : bihf;
    const float* __restrict__ bhh = dir ? bhhb : bhhf;

    // ---- zero out's slice: 4096 blocks x 256 thr x 4 float4 = 64 MiB ----
    {
        const int lb = (blockIdx.z * 512 + blockIdx.y) * 4 + blockIdx.x; // 0..4095
        float4 z4 = make_float4(0.f, 0.f, 0.f, 0.f);
        float4* zp = (float4*)out_zero + ((size_t)lb * 256 + threadIdx.x) * 4;
        zp[0] = z4; zp[1] = z4; zp[2] = z4; zp[3] = z4;
    }

    const int tid = threadIdx.x;
    const int w   = tid >> 6;                  // wave -> col group
    const int l   = tid & 63;
    const int q   = l >> 4;                    // k-subchunk / acc row group
    const int c   = l & 15;                    // frag row (A) / frag col (B,D)

    const int m0 = blockIdx.y * 64;            // 512 m-blocks
    const int n0 = blockIdx.x * 256 + w * 64;  // 4 n-blocks x 4 waves

    const float* xa = x + (size_t)(m0 + c) * DDIM + q * 8;
    const float* wa = W + (size_t)(n0 + c) * DDIM + q * 8;

    f32x4 acc[4][4];
#pragma unroll
    for (int rb = 0; rb < 4; ++rb)
#pragma unroll
        for (int nb = 0; nb < 4; ++nb) {
            f32x4 z; z[0] = 0.f; z[1] = 0.f; z[2] = 0.f; z[3] = 0.f;
            acc[rb][nb] = z;
        }

#pragma unroll 2
    for (int k0 = 0; k0 < DDIM; k0 += 32) {
        f16x8 afrag[4], bfrag[4];
#pragma unroll
        for (int rb = 0; rb < 4; ++rb) {
            const float4* p = (const float4*)(xa + (size_t)rb * 16 * DDIM + k0);
            float4 u0 = p[0], u1 = p[1];
            f16x8 v;
            v[0] = (_Float16)u0.x; v[1] = (_Float16)u0.y;
            v[2] = (_Float16)u0.z; v[3] = (_Float16)u0.w;
            v[4] = (_Float16)u1.x; v[5] = (_Float16)u1.y;
            v[6] = (_Float16)u1.z; v[7] = (_Float16)u1.w;
            afrag[rb] = v;
        }
#pragma unroll
        for (int nb = 0; nb < 4; ++nb) {
            const float4* p = (const float4*)(wa + (size_t)nb * 16 * DDIM + k0);
            float4 u0 = p[0], u1 = p[1];
            f16x8 v;
            v[0] = (_Float16)u0.x; v[1] = (_Float16)u0.y;
            v[2] = (_Float16)u0.z; v[3] = (_Float16)u0.w;
            v[4] = (_Float16)u1.x; v[5] = (_Float16)u1.y;
            v[6] = (_Float16)u1.z; v[7] = (_Float16)u1.w;
            bfrag[nb] = v;
        }
#pragma unroll
        for (int rb = 0; rb < 4; ++rb)
#pragma unroll
            for (int nb = 0; nb < 4; ++nb)
                acc[rb][nb] = __builtin_amdgcn_mfma_f32_16x16x32_f16(
                    afrag[rb], bfrag[nb], acc[rb][nb], 0, 0, 0);
    }

    // epilogue: + (b_ih + b_hh), cast fp16, store
#pragma unroll
    for (int nb = 0; nb < 4; ++nb) {
        const int col = n0 + nb * 16 + c;
        const float bias = bih[col] + bhh[col];
#pragma unroll
        for (int rb = 0; rb < 4; ++rb)
#pragma unroll
            for (int r = 0; r < 4; ++r) {
                const int m = m0 + rb * 16 + q * 4 + r;
                xwb[((size_t)dir * (L_SEQ * NB) + m) * GG + col] =
                    (_Float16)(acc[rb][nb][r] + bias);
            }
    }
}

// ---------------------------------------------------------------------------
// Phase 2: recurrence. 8 independent sync-groups, 32 blocks (co-resident).
// Group = (dir, batch-group of 16 rows); 4 blocks/group split 256 h-cols into
// 64-col slices. Block = 256 thr = 4 waves; lane (q,c) holds gates i,f,g,o of
// h-col j for batch rows b0+q*4+r in acc[0..3][r]. W_hh register-resident.
//
// Handshake (SELF-ANNOUNCING DATA, no flags/counters/Hbuf):
//  * The h-exchange medium IS `out`. Each out[tt][b][dir*256+j] slot is
//    written exactly once per run -> no phase recycling, no overwrite
//    hazard, no skew bound needed, and the natural step DAG is the only
//    dependency. out is pre-zeroed by gemm_xwb (same launch), so
//    "unwritten" == bit0 of the f32 pattern is 0.
//  * producer: val = as_uint(h*m) | 1  (mantissa bit0 = ready tag, 2^-23
//    perturbation) stored via global_store_dword sc0|sc1 (write-through to
//    the coherent point; fire-and-forget — no vmcnt, no flag hop).
//  * consumer (step s>0): polls the 64 f32 h-values of step s-1 it needs
//    DIRECTLY: 16x global_load_dwordx4 sc0|sc1 off one base reg with
//    immediate offsets, AND-reduce, check bit0. Detect = one L3 round trip
//    after the data lands — the flag round-trip and producer-side ack of
//    previous schemes are gone, and the 8-hot-line atomic-unit serialization
//    (16 spinning waves + 16 RMWs per line per step) is eliminated: polls
//    spread over the group's 16 rows x 256 cols of distinct lines.
//  * A-fragments: v_cvt_pk_bf16_f32 (RNE) on the polled f32s — recurrence
//    state math is bit-identical to the previous passing kernel; out keeps
//    full f32 h (bit0 noise only).
// ---------------------------------------------------------------------------
__global__ __launch_bounds__(256, 1) void lstm_recur(
    const _Float16* __restrict__ xwb,
    const float* __restrict__ Whh_f,
    const float* __restrict__ Whh_b,
    const float* __restrict__ mask,
    float* __restrict__ out)
{
    const int bid = blockIdx.x;           // 0..31
    const int grp = bid & 7;              // dir*4 + gb
    const int dir = grp >> 2;
    const int gb  = grp & 3;
    const int g   = bid >> 3;             // h-col slice 0..3

    const int tid = threadIdx.x;
    const int w   = tid >> 6;
    const int l   = tid & 63;
    const int q   = l >> 4;
    const int c   = l & 15;

    const int b0 = gb * 16;               // group's batch base
    const int j  = 64 * g + 16 * w + c;   // h column [0,256)

    // --- B fragments: W_hh slice, register resident ---
    // gate t: B[k][n=c] = W_hh[t*256 + j][k], lane k-range kt*32+q*8..+7
    const float* __restrict__ Whh = dir ? Whh_b : Whh_f;
    bf16x8 bfrag[4][8];
#pragma unroll
    for (int t = 0; t < 4; ++t) {
        const int gcol = t * HHALF + j;
#pragma unroll
        for (int kt = 0; kt < 8; ++kt) {
            const float4* wp = (const float4*)(Whh + (size_t)gcol * HHALF + kt * 32 + q * 8);
            float4 w0 = wp[0], w1 = wp[1];
            bf16x8 v;
            v[0] = (short)f2bf(w0.x); v[1] = (short)f2bf(w0.y);
            v[2] = (short)f2bf(w0.z); v[3] = (short)f2bf(w0.w);
            v[4] = (short)f2bf(w1.x); v[5] = (short)f2bf(w1.y);
            v[6] = (short)f2bf(w1.z); v[7] = (short)f2bf(w1.w);
            bfrag[t][kt] = v;
        }
    }

    float cstate[4] = {0.f, 0.f, 0.f, 0.f};

    for (int step = 0; step < L_SEQ; ++step) {
        const int tt = dir ? (L_SEQ - 1 - step) : step;

        // ---- prefetch (independent of h): xwb + mask; these fly while we
        //      poll below (poll's vmcnt(0) drains them too — needed anyway) --
        float xv[4][4];
        const _Float16* xp = xwb + ((size_t)(dir * L_SEQ + tt) * NB + b0 + q * 4) * GG + j;
#pragma unroll
        for (int t = 0; t < 4; ++t)
#pragma unroll
            for (int r = 0; r < 4; ++r)
                xv[t][r] = (float)xp[(size_t)r * GG + t * HHALF];
        float mv[4];
#pragma unroll
        for (int r = 0; r < 4; ++r) mv[r] = mask[tt * NB + b0 + q * 4 + r];

        // ---- A fragments: h_{step-1} rows b0..b0+15, full K=256 ----
        bf16x8 afrag[8];
        if (step > 0) {
            const int ttp = dir ? (L_SEQ - step) : (step - 1);
            // lane (q,c) reads row b0+c, cols kt*32+q*8..+7 (f32, tagged)
            const unsigned* pb = (const unsigned*)out
                + ((size_t)ttp * NB + b0 + c) * (2 * HHALF) + dir * HHALF + q * 8;
            u32x4 raw[16];
#define PLOAD(i, off) asm volatile("global_load_dwordx4 %0, %1, off offset:" #off " sc0 sc1" \
                                   : "=&v"(raw[i]) : "v"(pb))
            for (;;) {
                PLOAD(0, 0);    PLOAD(1, 16);
                PLOAD(2, 128);  PLOAD(3, 144);
                PLOAD(4, 256);  PLOAD(5, 272);
                PLOAD(6, 384);  PLOAD(7, 400);
                PLOAD(8, 512);  PLOAD(9, 528);
                PLOAD(10, 640); PLOAD(11, 656);
                PLOAD(12, 768); PLOAD(13, 784);
                PLOAD(14, 896); PLOAD(15, 912);
                asm volatile("s_waitcnt vmcnt(0)" ::: "memory");
                __builtin_amdgcn_sched_barrier(0);   // rule #18
                unsigned a = 0xFFFFFFFFu;
#pragma unroll
                for (int i = 0; i < 16; ++i)
                    a &= raw[i][0] & raw[i][1] & raw[i][2] & raw[i][3];
                if (__all((a & 1u) != 0u)) break;
            }
#undef PLOAD
            // pack f32 -> bf16 fragments (RNE via v_cvt_pk_bf16_f32)
#pragma unroll
            for (int kt = 0; kt < 8; ++kt) {
                union { u32x4 u; bf16x8 h; } cv;
                cv.u[0] = cvt_pk_bf16(raw[2 * kt][0],     raw[2 * kt][1]);
                cv.u[1] = cvt_pk_bf16(raw[2 * kt][2],     raw[2 * kt][3]);
                cv.u[2] = cvt_pk_bf16(raw[2 * kt + 1][0], raw[2 * kt + 1][1]);
                cv.u[3] = cvt_pk_bf16(raw[2 * kt + 1][2], raw[2 * kt + 1][3]);
                afrag[kt] = cv.h;
            }
        } else {
#pragma unroll
            for (int kt = 0; kt < 8; ++kt) {
                bf16x8 z = {0, 0, 0, 0, 0, 0, 0, 0};
                afrag[kt] = z;
            }
        }

        // ---- gates = xW (+biases) + h @ W_hh^T ----
        f32x4 acc[4];
#pragma unroll
        for (int t = 0; t < 4; ++t) {
            f32x4 a; a[0] = xv[t][0]; a[1] = xv[t][1]; a[2] = xv[t][2]; a[3] = xv[t][3];
            acc[t] = a;
        }
#pragma unroll
        for (int kt = 0; kt < 8; ++kt)
#pragma unroll
            for (int t = 0; t < 4; ++t)
                acc[t] = __builtin_amdgcn_mfma_f32_16x16x32_bf16(afrag[kt], bfrag[t][kt], acc[t], 0, 0, 0);

        // ---- elementwise + tagged publish directly into out ----
#pragma unroll
        for (int r = 0; r < 4; ++r) {
            float gi = acc[0][r], gf = acc[1][r], gg = acc[2][r], go = acc[3][r];
            float cn = fsigmoid(gf) * cstate[r] + fsigmoid(gi) * ftanh(gg);
            float h  = fsigmoid(go) * ftanh(cn);
            float m  = mv[r];
            h  *= m;
            cn *= m;
            cstate[r] = cn;
            const int b = b0 + q * 4 + r;
            unsigned val = __float_as_uint(h) | 1u;   // bit0 = ready tag (2^-23)
            st_dword_wt((unsigned*)out
                        + ((size_t)tt * NB + b) * (2 * HHALF) + dir * HHALF + j,
                        val);
        }
        // fire-and-forget: consumers detect via the tag; no ack, no flag.
    }
}

// ---------------------------------------------------------------------------
// Workspace layout:
//   [0, 128 MiB)   xwb fp16 [2][512][64][1024]     (Hbuf/flags: REMOVED —
//                                                   out itself is the
//                                                   h-exchange medium)
// Requires ws_size >= 134,217,728 bytes.
// ---------------------------------------------------------------------------
extern "C" void kernel_launch(void* const* d_in, const int* in_sizes, int n_in,
                              void* d_out, int out_size, void* d_ws, size_t ws_size,
                              hipStream_t stream)
{
    (void)in_sizes; (void)n_in; (void)out_size; (void)ws_size;
    const float* x     = (const float*)d_in[0];
    const float* mask  = (const float*)d_in[1];
    const float* Wih_f = (const float*)d_in[2];
    const float* Whh_f = (const float*)d_in[3];
    const float* bih_f = (const float*)d_in[4];
    const float* bhh_f = (const float*)d_in[5];
    const float* Wih_b = (const float*)d_in[6];
    const float* Whh_b = (const float*)d_in[7];
    const float* bih_b = (const float*)d_in[8];
    const float* bhh_b = (const float*)d_in[9];
    float* out = (float*)d_out;

    _Float16* xwb = (_Float16*)d_ws;

    // gemm_xwb also zero-fills `out` (ready-tag medium) before lstm_recur.
    hipLaunchKernelGGL(gemm_xwb, dim3(4, 512, 2), dim3(256), 0, stream,
                       x, Wih_f, Wih_b, bih_f, bhh_f, bih_b, bhh_b, xwb, out);

    hipLaunchKernelGGL(lstm_recur, dim3(32), dim3(256), 0, stream,
                       xwb, Whh_f, Whh_b, mask, out);
}